// Round 14
// baseline (397.567 us; speedup 1.0000x reference)
//
#include <hip/hip_runtime.h>

namespace {

constexpr int T = 4096;
constexpr int C = 128;
constexpr int H = 8;
constexpr int D = 16;
constexpr int BH = 16;                         // B*H
constexpr size_t PLANE = (size_t)BH * T * D;   // 1,048,576 elements per tensor
constexpr int NTILE = T / 32;                  // 128 key-tiles per bh
constexpr int VROWS = 17;                      // 16 d-rows + 1 ones-row
constexpr size_t VPLANE = (size_t)NTILE * VROWS * 32;  // per-bh Vt elements
constexpr int NBLK = 512;                      // fused grid; 2/CU exactly

using bf16x8 = __attribute__((ext_vector_type(8))) short;
using f32x16 = __attribute__((ext_vector_type(16))) float;

__device__ __forceinline__ uint32_t cvt_pk_bf16(float lo, float hi) {
  uint32_t r;
  asm("v_cvt_pk_bf16_f32 %0, %1, %2" : "=v"(r) : "v"(lo), "v"(hi));
  return r;
}
__device__ __forceinline__ float exp2_hw(float x) {
  float r;
  asm("v_exp_f32 %0, %1" : "=v"(r) : "v"(x));
  return r;
}

// Device-wide barrier (single-use per site per launch; counters zeroed by a
// hipMemsetAsync before each launch).  All 512 blocks are provably
// co-resident: LDS 68KB*2=136<=160KB and VGPR<=128 (launch_bounds) give
// exactly 2 blocks/CU x 256 CUs = 512.  Release/acquire via __threadfence
// (agent-scope: L2 writeback + invalidate) per Guideline 16.
__device__ __forceinline__ void gbar(unsigned* c) {
  __syncthreads();
  __threadfence();                      // release: flush this thread's writes
  __syncthreads();
  if (threadIdx.x == 0) {
    atomicAdd(c, 1u);
    while (atomicAdd(c, 0u) < (unsigned)NBLK) __builtin_amdgcn_s_sleep(2);
  }
  __syncthreads();
  __threadfence();                      // acquire: invalidate stale caches
}

// ---------------------------------------------------------------------------
// Fused kernel: phase1 qkv -> gbar -> phase2 attn -> gbar -> phase3 out_proj.
// One dispatch replaces three (the ~30us cross-round "other" that projection
// arithmetic cannot explain: per-dispatch setup/drain between short kernels).
// ---------------------------------------------------------------------------
__global__ __launch_bounds__(512, 2) void mha_fused(
    const float* __restrict__ x, const float* __restrict__ Wq,
    const float* __restrict__ Wk, const float* __restrict__ Wv,
    const float* __restrict__ Wp, const float* __restrict__ bp,
    unsigned short* __restrict__ Qbf, unsigned short* __restrict__ Kbf,
    unsigned short* __restrict__ Vt, float* __restrict__ att,
    float* __restrict__ out, unsigned* __restrict__ bar) {
  __shared__ __align__(16) char smem[69632];   // union of all phase layouts
  const int tid = threadIdx.x;
  const int ib = blockIdx.x;

  // ======== phase 1: QKV projection (768 units on 1024 half-blocks) ========
  // unit u = hf*512 + ib; halves with u>=768 idle through the same 5 syncs.
  {
    const int hf = tid >> 8;            // half 0/1 (256 threads each)
    const int t2 = tid & 255;
    const int u = hf * 512 + ib;
    const bool valid = u < 768;
    const int bm = u & 127;
    const int bn = valid ? (u >> 7) : 0;  // invalid -> harmless unit 0 math
    const int mat = bn >> 1;            // 0=Q 1=K 2=V
    const int c0 = (bn & 1) * 64;
    const float* W = (mat == 0) ? Wq : (mat == 1) ? Wk : Wv;
    const int t0 = bm * 64;
    const int tx = t2 & 15, ty = t2 >> 4;
    float (*Xs)[68] = reinterpret_cast<float(*)[68]>(smem + hf * 34816);
    float (*Wsh)[68] = reinterpret_cast<float(*)[68]>(smem + hf * 34816 + 17408);

    float acc[4][4] = {};
#pragma unroll 1
    for (int kh = 0; kh < 2; ++kh) {
      if (kh) __syncthreads();          // sync #2
      for (int f = t2; f < 1024; f += 256) {
        const int m = f >> 4, k4 = (f & 15) << 2;
        const float4 v = *(const float4*)(x + (size_t)(t0 + m) * C + kh * 64 + k4);
        Xs[k4 + 0][m] = v.x; Xs[k4 + 1][m] = v.y;
        Xs[k4 + 2][m] = v.z; Xs[k4 + 3][m] = v.w;
        const float4 uu = *(const float4*)(W + (size_t)(c0 + m) * C + kh * 64 + k4);
        Wsh[k4 + 0][m] = uu.x; Wsh[k4 + 1][m] = uu.y;
        Wsh[k4 + 2][m] = uu.z; Wsh[k4 + 3][m] = uu.w;
      }
      __syncthreads();                  // syncs #1, #3
#pragma unroll 8
      for (int k = 0; k < 64; ++k) {
        const float4 a = *(const float4*)&Xs[k][ty * 4];
        const float4 b = *(const float4*)&Wsh[k][tx * 4];
        const float av[4] = {a.x, a.y, a.z, a.w};
        const float bv[4] = {b.x, b.y, b.z, b.w};
#pragma unroll
        for (int i = 0; i < 4; ++i)
#pragma unroll
          for (int j = 0; j < 4; ++j) acc[i][j] = fmaf(av[i], bv[j], acc[i][j]);
      }
    }
    __syncthreads();                    // sync #4: reuse Xs as bf16 staging

    unsigned short* Ls = (unsigned short*)Xs;   // [64][72] bf16 per half
    if (mat < 2) {
      const float sc = (mat == 0) ? 0.25f * 1.4426950408889634f : 1.0f;
#pragma unroll
      for (int i = 0; i < 4; ++i) {
        const uint32_t u0 = cvt_pk_bf16(acc[i][0] * sc, acc[i][1] * sc);
        const uint32_t u1 = cvt_pk_bf16(acc[i][2] * sc, acc[i][3] * sc);
        *(uint32_t*)&Ls[(ty * 4 + i) * 72 + tx * 4]     = u0;
        *(uint32_t*)&Ls[(ty * 4 + i) * 72 + tx * 4 + 2] = u1;
      }
      __syncthreads();                  // sync #5
      if (valid) {
        unsigned short* dst = (mat == 0) ? Qbf : Kbf;
        const int lane = t2 & 63, hp = t2 >> 6;
        const int tr = t0 + lane, b = tr >> 12, t = tr & (T - 1);
        const int head = (c0 >> 4) + hp;
        unsigned short* base = dst + (((size_t)(b * H + head)) * T + t) * D;
#pragma unroll
        for (int p = 0; p < 2; ++p)
          *(uint4*)(base + p * 8) =
              *(const uint4*)&Ls[lane * 72 + hp * 16 + p * 8];
      }
    } else {
#pragma unroll
      for (int j = 0; j < 4; ++j) {     // Ls[c][t] (transposed)
        const uint32_t u0 = cvt_pk_bf16(acc[0][j], acc[1][j]);
        const uint32_t u1 = cvt_pk_bf16(acc[2][j], acc[3][j]);
        *(uint32_t*)&Ls[(tx * 4 + j) * 72 + ty * 4]     = u0;
        *(uint32_t*)&Ls[(tx * 4 + j) * 72 + ty * 4 + 2] = u1;
      }
      __syncthreads();                  // sync #5
      if (valid) {
        const int c = t2 >> 2;
        const int b = t0 >> 12;
        const int head = (c0 + c) >> 4, dvv = (c0 + c) & 15;
        const int tile0 = (t0 & (T - 1)) >> 5;
        unsigned short* vbase =
            Vt + (((size_t)(b * H + head) * NTILE + tile0) * VROWS + dvv) * 32;
#pragma unroll
        for (int it = 0; it < 2; ++it) {
          const int part = (t2 & 3) + 4 * it;
          unsigned short* row = vbase + (part >> 2) * (VROWS * 32);
          const int q = part & 3;
          *(uint2*)(row + 4 * q) = *(const uint2*)&Ls[c * 72 + part * 8];
          *(uint2*)(row + 16 + 4 * q) =
              *(const uint2*)&Ls[c * 72 + part * 8 + 4];
        }
        if (t2 < 8) {                   // ones row for 4 heads x 2 tiles
          const int headx = (c0 >> 4) + (t2 >> 1);
          const int tilex = tile0 + (t2 & 1);
          unsigned short* orow =
              Vt + (((size_t)(b * H + headx) * NTILE + tilex) * VROWS + 16) * 32;
          const uint4 ones = make_uint4(0x3F803F80u, 0x3F803F80u,
                                        0x3F803F80u, 0x3F803F80u);
#pragma unroll
          for (int q = 0; q < 4; ++q) *(uint4*)(orow + q * 8) = ones;
        }
      }
    }
  }

  gbar(bar + 0);                        // all Q/K/V visible device-wide

  // ======== phase 2: attention (r12 body: 2-tile waves, 2-deep prefetch,
  //          no-max softmax, ones-row denominator) ========
  {
    float (*Po)[2][32][17] = reinterpret_cast<float(*)[2][32][17]>(smem);
    const int w = tid >> 6, l = tid & 63;
    const int lane31 = l & 31, h = l >> 5;
    const int dvx = (lane31 == 16) ? 16 : (l & 15);
    const int bh = 2 * (ib & 7) + ((ib >> 3) & 1);  // XCD x <- bh {2x,2x+1}
    const int j = ib >> 4;                          // 0..31
    const int superA = 63 - j, superB = j;
    const int nsA = 2 * superA + 2, nsB = 2 * superB + 2;

    const unsigned short* Qp = Qbf + (size_t)bh * T * D;
    const unsigned short* Kp = Kbf + (size_t)bh * T * D;
    const unsigned short* Vp = Vt + (size_t)bh * VPLANE;

    const size_t koff = (size_t)lane31 * D + 8 * h;
    const size_t voff = (size_t)dvx * 32 + 16 * h;

    struct Frag { bf16x8 k, vA, vB; };
    auto ld = [&](int s) {
      Frag f;
      f.k = *(const bf16x8*)(Kp + (size_t)s * (32 * D) + koff);
      const unsigned short* vb = Vp + (size_t)s * (VROWS * 32) + voff;
      f.vA = *(const bf16x8*)(vb);
      f.vB = *(const bf16x8*)(vb + 8);
      return f;
    };

    auto run_phase = [&](int sup, int s0, int ns) {
      const int tq0 = 2 * sup, tq1 = 2 * sup + 1;
      const int qidx0 = sup * 64 + lane31, qidx1 = qidx0 + 32;
      const bf16x8 qf0 = *(const bf16x8*)(Qp + (size_t)qidx0 * D + 8 * h);
      const bf16x8 qf1 = *(const bf16x8*)(Qp + (size_t)qidx1 * D + 8 * h);
      f32x16 acc0 = {}, acc1 = {};

      auto half_step = [&](const Frag& f, const bf16x8& qf, f32x16& acc,
                           int s, int tq, int qidx) {
        f32x16 sc = {};
        __builtin_amdgcn_s_setprio(1);
        sc = __builtin_amdgcn_mfma_f32_32x32x16_bf16(f.k, qf, sc, 0, 0, 0);
        __builtin_amdgcn_s_setprio(0);
        if (s >= tq) {                  // diag or dead step: causal mask
          const int k0 = s * 32;
#pragma unroll
          for (int r = 0; r < 16; ++r) {
            const int key = k0 + (r & 3) + 8 * (r >> 2) + 4 * h;
            if (key > qidx) sc[r] = -1e30f;
          }
        }
#pragma unroll
        for (int r = 0; r < 16; ++r) sc[r] = exp2_hw(sc[r]);
        union PF { bf16x8 v; uint32_t u[4]; } pa, pb;
        pa.u[0] = cvt_pk_bf16(sc[0], sc[1]);
        pa.u[1] = cvt_pk_bf16(sc[2], sc[3]);
        pa.u[2] = cvt_pk_bf16(sc[4], sc[5]);
        pa.u[3] = cvt_pk_bf16(sc[6], sc[7]);
        pb.u[0] = cvt_pk_bf16(sc[8], sc[9]);
        pb.u[1] = cvt_pk_bf16(sc[10], sc[11]);
        pb.u[2] = cvt_pk_bf16(sc[12], sc[13]);
        pb.u[3] = cvt_pk_bf16(sc[14], sc[15]);
        __builtin_amdgcn_s_setprio(1);
        acc = __builtin_amdgcn_mfma_f32_32x32x16_bf16(f.vA, pa.v, acc, 0, 0, 0);
        acc = __builtin_amdgcn_mfma_f32_32x32x16_bf16(f.vB, pb.v, acc, 0, 0, 0);
        __builtin_amdgcn_s_setprio(0);
      };

      const int sv = (s0 < ns) ? s0 : 0;
      Frag cur = ld(sv);
      Frag n1 = ld(s0 + 8 < ns ? s0 + 8 : sv);
#pragma unroll 1
      for (int s = s0; s < ns; s += 8) {
        const int s2 = (s + 16 < ns) ? s + 16 : s;
        const Frag n2 = ld(s2);
        half_step(cur, qf0, acc0, s, tq0, qidx0);
        half_step(cur, qf1, acc1, s, tq1, qidx1);
        cur = n1;
        n1 = n2;
      }

#pragma unroll
      for (int r = 0; r < 8; ++r) {
        const int dj = (r & 3) + 8 * (r >> 2) + 4 * h;
        Po[w][0][lane31][dj] = acc0[r];
        Po[w][1][lane31][dj] = acc1[r];
      }
      if (l < 32) {                     // row 16 = sum(P)
        Po[w][0][lane31][16] = acc0[8];
        Po[w][1][lane31][16] = acc1[8];
      }
    };

    auto merge = [&](int sup, int tt) {
      const int qidx = sup * 64 + tt * 32 + lane31;
      float L = 0.f, od[8] = {};
#pragma unroll
      for (int p = 0; p < 8; ++p) {
        L += Po[p][tt][lane31][16];
#pragma unroll
        for (int r = 0; r < 8; ++r) {
          const int dj = (r & 3) + 8 * (r >> 2) + 4 * h;
          od[r] += Po[p][tt][lane31][dj];
        }
      }
      const float inv = 1.f / L;
      float* base = att + ((size_t)bh * T + qidx) * D;
      *(float4*)(base + 4 * h) =
          make_float4(od[0] * inv, od[1] * inv, od[2] * inv, od[3] * inv);
      *(float4*)(base + 8 + 4 * h) =
          make_float4(od[4] * inv, od[5] * inv, od[6] * inv, od[7] * inv);
    };

    run_phase(superA, w, nsA);
    __syncthreads();
    if (w < 2) merge(superA, w);
    __syncthreads();
    const int cA = (nsA - w + 7) >> 3;
    const int sB0 = w + 8 * cA - nsA;
    run_phase(superB, sB0, nsB);
    __syncthreads();
    if (w < 2) merge(superB, w);
  }

  gbar(bar + 1);                        // all att visible device-wide

  // ======== phase 3: output projection (one 32x64 tile per block) ========
  {
    float (*As)[36] = reinterpret_cast<float(*)[36]>(smem);          // 9.2KB
    float (*Bs)[68] = reinterpret_cast<float(*)[68]>(smem + 9728);   // 17.4KB
    const int t0 = (ib >> 1) * 32;
    const int c0 = (ib & 1) * 64;
    const int tx = tid & 15, ty2 = tid >> 4;    // 16 col-groups x 32 rows

    float acc[4] = {};
#pragma unroll 1
    for (int kh = 0; kh < 2; ++kh) {
      if (kh) __syncthreads();
      {
        const int f = tid;              // 512 threads stage 512 float4s
        const int mm = f & 31;
        const int cpl = (f >> 5) << 2;
        const int cp = kh * 64 + cpl;
        const int tr = t0 + mm;
        const int b = tr >> 12, t = tr & (T - 1);
        const int hh = cp >> 4, d0 = cp & 15;
        const float4 v =
            *(const float4*)(att + (((size_t)b * H + hh) * T + t) * D + d0);
        As[cpl + 0][mm] = v.x; As[cpl + 1][mm] = v.y;
        As[cpl + 2][mm] = v.z; As[cpl + 3][mm] = v.w;
      }
      for (int f = tid; f < 1024; f += 512) {
        const int n = f >> 4;
        const int kk = (f & 15) << 2;
        const float4 v =
            *(const float4*)(Wp + (size_t)(c0 + n) * C + kh * 64 + kk);
        Bs[kk + 0][n] = v.x; Bs[kk + 1][n] = v.y;
        Bs[kk + 2][n] = v.z; Bs[kk + 3][n] = v.w;
      }
      __syncthreads();
#pragma unroll 8
      for (int k = 0; k < 64; ++k) {
        const float a = As[k][ty2];     // 16-lane broadcast
        const float4 b = *(const float4*)&Bs[k][tx * 4];
        acc[0] = fmaf(a, b.x, acc[0]);
        acc[1] = fmaf(a, b.y, acc[1]);
        acc[2] = fmaf(a, b.z, acc[2]);
        acc[3] = fmaf(a, b.w, acc[3]);
      }
    }

    const float4 bias = *(const float4*)(bp + c0 + tx * 4);
    const int tr = t0 + ty2;
    *(float4*)(out + (size_t)tr * C + c0 + tx * 4) =
        make_float4(acc[0] + bias.x, acc[1] + bias.y,
                    acc[2] + bias.z, acc[3] + bias.w);
  }
}

}  // namespace

extern "C" void kernel_launch(void* const* d_in, const int* in_sizes, int n_in,
                              void* d_out, int out_size, void* d_ws, size_t ws_size,
                              hipStream_t stream) {
  // setup_inputs order: x, Wk, Wq, Wv, Wp, bp
  const float* x  = (const float*)d_in[0];
  const float* Wk = (const float*)d_in[1];
  const float* Wq = (const float*)d_in[2];
  const float* Wv = (const float*)d_in[3];
  const float* Wp = (const float*)d_in[4];
  const float* bp = (const float*)d_in[5];

  float* att = (float*)d_ws;                             // 4 MiB fp32
  unsigned short* Qbf = (unsigned short*)(att + PLANE);  // 2 MiB bf16
  unsigned short* Kbf = Qbf + PLANE;                     // 2 MiB
  unsigned short* Vtb = Kbf + PLANE;                     // 2.13 MiB (VROWS=17)
  unsigned* bar = (unsigned*)(Vtb + BH * VPLANE);        // 2 barrier counters

  hipMemsetAsync(bar, 0, 2 * sizeof(unsigned), stream);  // zero per replay
  mha_fused<<<dim3(NBLK), 512, 0, stream>>>(x, Wq, Wk, Wv, Wp, bp, Qbf, Kbf,
                                            Vtb, att, (float*)d_out, bar);
}